// Round 2
// baseline (287.839 us; speedup 1.0000x reference)
//
#include <hip/hip_runtime.h>

#define NROWS 2097152
#define W 16

__global__ __launch_bounds__(256) void cel_weight_kernel(
    const float* __restrict__ predict,
    const float* __restrict__ target,
    const float* __restrict__ penalty,
    float* __restrict__ out)
{
    __shared__ float s_pen[W * W];
    __shared__ float s_part[4];

    const int tid = threadIdx.x;
    if (tid < W * W) s_pen[tid] = penalty[tid];
    __syncthreads();

    const int quad = tid & 3;                       // lane-in-quad: which float4 of the row
    const int gthread = blockIdx.x * blockDim.x + tid;
    const int q0 = gthread >> 2;                    // global quad id = row id
    const int nquads = (gridDim.x * blockDim.x) >> 2;
    const int jbase = quad * 4;                     // this lane's column base within the row

    float acc = 0.0f;

    for (int row = q0; row < NROWS; row += nquads) {
        // Fully coalesced: lane i of the wave loads 16B at wave_base + i*16B.
        const size_t off = (size_t)row * W + jbase;
        float4 p = *(const float4*)(predict + off);
        float4 t = *(const float4*)(target + off);

        // ---- local argmax over this lane's 4 predict elements (first-index tie-break)
        float pmax = p.x; int pidx = jbase;
        if (p.y > pmax) { pmax = p.y; pidx = jbase + 1; }
        if (p.z > pmax) { pmax = p.z; pidx = jbase + 2; }
        if (p.w > pmax) { pmax = p.w; pidx = jbase + 3; }
        // combine across the quad (xor 1, xor 2 stay within the quad -> DPP quad_perm)
        #pragma unroll
        for (int d = 1; d <= 2; d <<= 1) {
            float om = __shfl_xor(pmax, d);
            int   oi = __shfl_xor(pidx, d);
            if (om > pmax || (om == pmax && oi < pidx)) { pmax = om; pidx = oi; }
        }

        // ---- softmax denominator: sum exp(x - rowmax), numerator at argmax = 1
        float lsum = __expf(p.x - pmax) + __expf(p.y - pmax)
                   + __expf(p.z - pmax) + __expf(p.w - pmax);
        lsum += __shfl_xor(lsum, 1);
        lsum += __shfl_xor(lsum, 2);

        // ---- target argmax
        float tmax = t.x; int tidx = jbase;
        if (t.y > tmax) { tmax = t.y; tidx = jbase + 1; }
        if (t.z > tmax) { tmax = t.z; tidx = jbase + 2; }
        if (t.w > tmax) { tmax = t.w; tidx = jbase + 3; }
        #pragma unroll
        for (int d = 1; d <= 2; d <<= 1) {
            float om = __shfl_xor(tmax, d);
            int   oi = __shfl_xor(tidx, d);
            if (om > tmax || (om == tmax && oi < tidx)) { tmax = om; tidx = oi; }
        }

        // one lane per quad contributes the row's term
        if (quad == 0) {
            float wgt = (pidx == tidx) ? 0.0f : s_pen[tidx * W + pidx];
            acc += wgt / lsum;
        }
    }

    // wave-64 reduction
    #pragma unroll
    for (int off = 32; off > 0; off >>= 1)
        acc += __shfl_down(acc, off);

    const int lane = tid & 63;
    const int wid  = tid >> 6;
    if (lane == 0) s_part[wid] = acc;
    __syncthreads();

    if (tid == 0) {
        float tot = s_part[0] + s_part[1] + s_part[2] + s_part[3];
        atomicAdd(out, tot * (1.0f / (float)NROWS));
    }
}

extern "C" void kernel_launch(void* const* d_in, const int* in_sizes, int n_in,
                              void* d_out, int out_size, void* d_ws, size_t ws_size,
                              hipStream_t stream)
{
    const float* predict = (const float*)d_in[0];
    const float* target  = (const float*)d_in[1];
    const float* penalty = (const float*)d_in[2];
    float* out = (float*)d_out;

    // d_out is poisoned (0xAA) before every replay — zero it on-stream.
    hipMemsetAsync(out, 0, sizeof(float) * out_size, stream);

    dim3 grid(4096), block(256);
    cel_weight_kernel<<<grid, block, 0, stream>>>(predict, target, penalty, out);
}